// Round 1
// baseline (1694.703 us; speedup 1.0000x reference)
//
#include <hip/hip_runtime.h>

__global__ void k_fill(unsigned* p, int n, unsigned v) {
    int i = blockIdx.x * blockDim.x + threadIdx.x;
    if (i < n) p[i] = v;
}

// ---------------- CSR build (graph identical across layers; built once) ----------------
__global__ void k_hist(const int* __restrict__ ei, int E, int* __restrict__ deg) {
    int e = blockIdx.x * blockDim.x + threadIdx.x;
    if (e < E) atomicAdd(&deg[ei[E + e]], 1);
}

__global__ void k_scan_blocks(const int* __restrict__ deg, int N,
                              int* __restrict__ excl, int* __restrict__ parts) {
    __shared__ int s[256];
    int t = threadIdx.x, i = blockIdx.x * 256 + t;
    int v = (i < N) ? deg[i] : 0;
    s[t] = v;
    __syncthreads();
    int acc = v;
    for (int off = 1; off < 256; off <<= 1) {
        int add = (t >= off) ? s[t - off] : 0;
        __syncthreads();
        acc += add;
        s[t] = acc;
        __syncthreads();
    }
    if (i < N) excl[i] = acc - v;
    if (t == 255) parts[blockIdx.x] = acc;
}

__global__ void k_scan_parts(int* __restrict__ parts, int nb) {
    __shared__ int s[256];
    int t = threadIdx.x;
    int v = (t < nb) ? parts[t] : 0;
    s[t] = v;
    __syncthreads();
    int acc = v;
    for (int off = 1; off < 256; off <<= 1) {
        int add = (t >= off) ? s[t - off] : 0;
        __syncthreads();
        acc += add;
        s[t] = acc;
        __syncthreads();
    }
    if (t < nb) parts[t] = acc - v;
}

__global__ void k_scan_add(const int* __restrict__ excl, const int* __restrict__ parts,
                           int* __restrict__ row_ptr, int* __restrict__ cursor, int N) {
    int i = blockIdx.x * blockDim.x + threadIdx.x;
    if (i >= N) return;
    int r = excl[i] + parts[i >> 8];
    row_ptr[i] = r;
    cursor[i] = r;
}

__global__ void k_scatter(const int* __restrict__ ei, int E, int* __restrict__ cursor,
                          int2* __restrict__ elist) {
    int e = blockIdx.x * blockDim.x + threadIdx.x;
    if (e >= E) return;
    int d = ei[E + e];
    int j = atomicAdd(&cursor[d], 1);
    elist[j] = make_int2(ei[e], e);
}

// permute edge_attr into CSR order: ea_s[j] = ea[elist[j].y]  (8 threads per edge)
__global__ void k_reorder(const int2* __restrict__ elist, const float* __restrict__ ea, int E,
                          float4* __restrict__ ea_s) {
    int idx = blockIdx.x * blockDim.x + threadIdx.x;
    int j = idx >> 3, q = idx & 7;
    if (j >= E) return;
    ea_s[(size_t)j * 8 + q] = ((const float4*)ea)[(size_t)elist[j].y * 8 + q];
}

// ---------------- Dual GEMM: out{l,r} = A @ W{l,r} + b{l,r} ----------------
template <int M, int RW>
__global__ __launch_bounds__(256) void k_gemm2(const float* __restrict__ A,
                                               const float* __restrict__ Wl, const float* __restrict__ bl,
                                               const float* __restrict__ Wr, const float* __restrict__ br,
                                               float* __restrict__ outl, float* __restrict__ outr) {
    constexpr int TX = M / 4;
    __shared__ float sA[32][68];
    __shared__ float sW[32][M];
    const float* W    = blockIdx.y ? Wr : Wl;
    const float* bias = blockIdx.y ? br : bl;
    float* out        = blockIdx.y ? outr : outl;
    int t = threadIdx.x;
    int tx = t % TX, ty = t / TX;
    int r0 = blockIdx.x * 64;
    float acc[RW][4] = {};
    for (int kt = 0; kt < 128; kt += 32) {
        for (int l = t; l < 512; l += 256) {
            int row = l >> 3, kq = (l & 7) << 2;
            float4 a = *(const float4*)&A[(size_t)(r0 + row) * 128 + kt + kq];
            sA[kq + 0][row] = a.x; sA[kq + 1][row] = a.y;
            sA[kq + 2][row] = a.z; sA[kq + 3][row] = a.w;
        }
        for (int l = t; l < 32 * M / 4; l += 256) {
            int kk = (l * 4) / M, cc = (l * 4) % M;
            *(float4*)&sW[kk][cc] = *(const float4*)&W[(size_t)(kt + kk) * M + cc];
        }
        __syncthreads();
#pragma unroll
        for (int k = 0; k < 32; k++) {
            float4 w = *(float4*)&sW[k][tx * 4];
            float ar[RW];
#pragma unroll
            for (int i = 0; i < RW; i += 4) {
                float4 a = *(float4*)&sA[k][ty * RW + i];
                ar[i] = a.x; ar[i + 1] = a.y; ar[i + 2] = a.z; ar[i + 3] = a.w;
            }
#pragma unroll
            for (int i = 0; i < RW; i++) {
                acc[i][0] += ar[i] * w.x; acc[i][1] += ar[i] * w.y;
                acc[i][2] += ar[i] * w.z; acc[i][3] += ar[i] * w.w;
            }
        }
        __syncthreads();
    }
    float4 b = *(const float4*)&bias[tx * 4];
#pragma unroll
    for (int i = 0; i < RW; i++) {
        float4 v;
        v.x = acc[i][0] + b.x; v.y = acc[i][1] + b.y;
        v.z = acc[i][2] + b.z; v.w = acc[i][3] + b.w;
        *(float4*)&out[(size_t)(r0 + ty * RW + i) * M + tx * 4] = v;
    }
}

// ---------------- Fused per-dst GATv2 aggregation (CSR, zero atomics) ----------------
// Layout v2: 2 channels per lane, 32-lane halves.
//   H==2: half = head index; lanes 0-31 own head 0 (channels 2*c2, 2*c2+1),
//         lanes 32-63 own head 1. Att-dot reduces over 32 lanes (5 shuffle levels),
//         covering BOTH heads in the same butterfly. No cross-half exchange at all.
//   H==1: half = edge parity; the two halves process two different edges
//         concurrently (each half reduces its own logit in the shared 5-level
//         butterfly); one cross-half combine of acc/den at the end.
// __launch_bounds__(256,2) so the 64-float rWe array stays register-resident
// (at 64-VGPR cap the compiler rematerialized We loads inside the edge loop).
template <int H, bool RELU, bool SORTED>
__global__ __launch_bounds__(256, 2) void k_agg(const float* __restrict__ xl, const float* __restrict__ xr,
                                                const float* __restrict__ ea, const float4* __restrict__ ea_s,
                                                const int2* __restrict__ elist,
                                                const int* __restrict__ row_ptr, const int* __restrict__ deg,
                                                const float* __restrict__ We, const float* __restrict__ att,
                                                const float* __restrict__ bias, float* __restrict__ out, int N) {
    constexpr int HC = H * 64;
    int tid = threadIdx.x, wv = tid >> 6, lane = tid & 63;
    int half = lane >> 5, c2 = lane & 31;
    int col = (H == 2 ? half * 64 : 0) + 2 * c2;
    int n = blockIdx.x * 4 + wv;
    if (n >= N) return;

    float2 rWe[32];
#pragma unroll
    for (int k = 0; k < 32; k++) rWe[k] = *(const float2*)&We[k * HC + col];
    float2 attv = *(const float2*)&att[col];
    float2 bv   = *(const float2*)&bias[col];
    float2 xrv  = *(const float2*)&xr[(size_t)n * HC + col];

    int start = row_ptr[n], d = deg[n];
    float2 acc = make_float2(0.f, 0.f);
    float den = 0.f;

    // compute un-reduced logit contribution p (2 channels) + xl pair for CSR slot
    auto edge_pre = [&](int slot, float2& xlv, float& p) {
        int2 sp = elist[slot];
        const float4* eap = SORTED ? (ea_s + (size_t)slot * 8)
                                   : (const float4*)(ea + (size_t)sp.y * 32);
        xlv = *(const float2*)&xl[(size_t)sp.x * HC + col];
        float2 ee = make_float2(0.f, 0.f);
#pragma unroll
        for (int kq = 0; kq < 8; kq++) {
            float4 v = eap[kq];
            ee.x = fmaf(v.x, rWe[kq * 4 + 0].x, ee.x); ee.y = fmaf(v.x, rWe[kq * 4 + 0].y, ee.y);
            ee.x = fmaf(v.y, rWe[kq * 4 + 1].x, ee.x); ee.y = fmaf(v.y, rWe[kq * 4 + 1].y, ee.y);
            ee.x = fmaf(v.z, rWe[kq * 4 + 2].x, ee.x); ee.y = fmaf(v.z, rWe[kq * 4 + 2].y, ee.y);
            ee.x = fmaf(v.w, rWe[kq * 4 + 3].x, ee.x); ee.y = fmaf(v.w, rWe[kq * 4 + 3].y, ee.y);
        }
        float v0 = xlv.x + xrv.x + ee.x;
        float v1 = xlv.y + xrv.y + ee.y;
        v0 = v0 > 0.f ? v0 : 0.2f * v0;
        v1 = v1 > 0.f ? v1 : 0.2f * v1;
        p = attv.x * v0 + attv.y * v1;
    };

    if constexpr (H == 2) {
        int j = 0;
        for (; j + 2 <= d; j += 2) {   // unroll x2: two independent chains interleave
            float2 xla, xlb;
            float pa, pb;
            edge_pre(start + j, xla, pa);
            edge_pre(start + j + 1, xlb, pb);
#pragma unroll
            for (int m = 16; m; m >>= 1) { pa += __shfl_xor(pa, m); pb += __shfl_xor(pb, m); }
            float exa = __expf(pa), exb = __expf(pb);
            acc.x = fmaf(exa, xla.x, acc.x); acc.y = fmaf(exa, xla.y, acc.y);
            acc.x = fmaf(exb, xlb.x, acc.x); acc.y = fmaf(exb, xlb.y, acc.y);
            den += exa + exb;
        }
        if (j < d) {
            float2 xla;
            float pa;
            edge_pre(start + j, xla, pa);
#pragma unroll
            for (int m = 16; m; m >>= 1) pa += __shfl_xor(pa, m);
            float exa = __expf(pa);
            acc.x = fmaf(exa, xla.x, acc.x); acc.y = fmaf(exa, xla.y, acc.y);
            den += exa;
        }
    } else {
        // two edges per wave-iteration via half split; unroll x2 pairs -> 4 edges/iter
        for (int j = 0; j < d; j += 4) {
            {
                int jj = j + half;
                bool valid = jj < d;
                int slot = start + (valid ? jj : j);
                float2 xla;
                float pa;
                edge_pre(slot, xla, pa);
#pragma unroll
                for (int m = 16; m; m >>= 1) pa += __shfl_xor(pa, m);
                float exa = valid ? __expf(pa) : 0.f;
                acc.x = fmaf(exa, xla.x, acc.x); acc.y = fmaf(exa, xla.y, acc.y);
                den += exa;
            }
            if (j + 2 < d) {
                int jj = j + 2 + half;
                bool valid = jj < d;
                int slot = start + (valid ? jj : j);
                float2 xlb;
                float pb;
                edge_pre(slot, xlb, pb);
#pragma unroll
                for (int m = 16; m; m >>= 1) pb += __shfl_xor(pb, m);
                float exb = valid ? __expf(pb) : 0.f;
                acc.x = fmaf(exb, xlb.x, acc.x); acc.y = fmaf(exb, xlb.y, acc.y);
                den += exb;
            }
        }
        // combine the two halves (they aggregated disjoint edge subsets)
        acc.x += __shfl_xor(acc.x, 32);
        acc.y += __shfl_xor(acc.y, 32);
        den   += __shfl_xor(den, 32);
    }

    float inv = 1.f / (den + 1e-16f);
    float o0 = acc.x * inv + bv.x;
    float o1 = acc.y * inv + bv.y;
    if (RELU) { o0 = fmaxf(o0, 0.f); o1 = fmaxf(o1, 0.f); }
    *(float2*)&out[(size_t)n * HC + col] = make_float2(o0, o1);
}

// ---------------- gate MLP: gate[n] = exp(relu(h[n]@G1w+G1b)@G2w + G2b) ----------------
__global__ __launch_bounds__(256) void k_gate(const float* __restrict__ h, const float* __restrict__ G1w,
                                              const float* __restrict__ G1b, const float* __restrict__ G2w,
                                              const float* __restrict__ G2b,
                                              float* __restrict__ gate, int N) {
    __shared__ float sH[64][64];
    __shared__ float part[64][2];
    int t = threadIdx.x;
    int n0 = blockIdx.x * 64;
    for (int l = t; l < 1024; l += 256) {
        float4 v = ((const float4*)(h + (size_t)n0 * 64))[l];
        int n = l >> 4, kq = (l & 15) << 2;
        *(float4*)&sH[n][kq] = v;
    }
    int c = t & 127, half = t >> 7;
    float rW[64];
#pragma unroll
    for (int k = 0; k < 64; k++) rW[k] = G1w[k * 128 + c];
    float g1b = G1b[c], g2w = G2w[c];
    __syncthreads();
    for (int nn = 0; nn < 32; nn++) {
        int n = half * 32 + nn;
        float acc = g1b;
#pragma unroll
        for (int k = 0; k < 64; k += 4) {
            float4 hv = *(const float4*)&sH[n][k];
            acc = fmaf(hv.x, rW[k], acc);
            acc = fmaf(hv.y, rW[k + 1], acc);
            acc = fmaf(hv.z, rW[k + 2], acc);
            acc = fmaf(hv.w, rW[k + 3], acc);
        }
        acc = acc > 0.f ? acc : 0.f;
        float p = acc * g2w;
#pragma unroll
        for (int m = 32; m; m >>= 1) p += __shfl_xor(p, m);
        if ((t & 63) == 0) part[n][(t >> 6) & 1] = p;
    }
    __syncthreads();
    if (t < 64) gate[n0 + t] = __expf(part[t][0] + part[t][1] + G2b[0]);
}

// ---------------- pooling: one block per graph (batch sorted -> binary search range) ----------------
__global__ __launch_bounds__(256) void k_pool(const float* __restrict__ h, const float* __restrict__ gate,
                                              const int* __restrict__ batch,
                                              float* __restrict__ pooled, int N) {
    int g = blockIdx.x;
    int lo = 0, hi = N;
    while (lo < hi) { int mid = (lo + hi) >> 1; if (batch[mid] < g) lo = mid + 1; else hi = mid; }
    int start = lo;
    lo = 0; hi = N;
    while (lo < hi) { int mid = (lo + hi) >> 1; if (batch[mid] < g + 1) lo = mid + 1; else hi = mid; }
    int end = lo;
    int t = threadIdx.x, wv = t >> 6, lane = t & 63;
    float acc = 0.f, den = 0.f;
    for (int n = start + wv; n < end; n += 4) {
        float gv = gate[n];
        acc = fmaf(gv, h[(size_t)n * 64 + lane], acc);
        den += gv;   // same across lanes of this wave
    }
    __shared__ float sacc[4][64];
    __shared__ float sden[4];
    sacc[wv][lane] = acc;
    if (lane == 0) sden[wv] = den;
    __syncthreads();
    if (wv == 0) {
        float a = sacc[0][lane] + sacc[1][lane] + sacc[2][lane] + sacc[3][lane];
        float d = sden[0] + sden[1] + sden[2] + sden[3] + 1e-16f;
        pooled[g * 64 + lane] = a / d;
    }
}

__global__ void k_final(const float* __restrict__ pooled, const float* __restrict__ Wreg,
                        const float* __restrict__ breg, float* __restrict__ out) {
    int g = threadIdx.x;
    float acc = breg[0];
    for (int c = 0; c < 64; c++) acc += pooled[g * 64 + c] * Wreg[c];
    out[g] = acc;
}

extern "C" void kernel_launch(void* const* d_in, const int* in_sizes, int n_in,
                              void* d_out, int out_size, void* d_ws, size_t ws_size,
                              hipStream_t stream) {
    const float* x  = (const float*)d_in[0];
    const float* ea = (const float*)d_in[1];
    const int* ei    = (const int*)d_in[2];
    const int* batch = (const int*)d_in[3];
    auto ff = [&](int i) { return (const float*)d_in[i]; };
    const float *W1l = ff(4), *b1l = ff(5), *W1r = ff(6), *b1r = ff(7), *W1e = ff(8),
                *att1 = ff(9), *bias1 = ff(10);
    const float *W2l = ff(11), *b2l = ff(12), *W2r = ff(13), *b2r = ff(14), *W2e = ff(15),
                *att2 = ff(16), *bias2 = ff(17);
    const float *W3l = ff(18), *b3l = ff(19), *W3r = ff(20), *b3r = ff(21), *W3e = ff(22),
                *att3 = ff(23), *bias3 = ff(24);
    const float *G1w = ff(25), *G1b = ff(26), *G2w = ff(27), *G2b = ff(28), *Wreg = ff(29),
                *breg = ff(30);

    const int N = in_sizes[0] / 128;  // 40000
    const int E = in_sizes[2] / 2;    // 640000

    char* ws = (char*)d_ws;
    float*  bufA    = (float*)(ws);              // [N,128]
    float*  bufB    = (float*)(ws + 20480000);   // [N,128]
    float*  bufH    = (float*)(ws + 40960000);   // [N,128]
    int2*   elist   = (int2*)(ws + 61440000);    // [E] (src, edge_id)
    int*    row_ptr = (int*)(ws + 66560000);     // [N]
    int*    deg     = (int*)(ws + 66720000);     // [N]
    int*    cursor  = (int*)(ws + 66880000);     // [N]
    int*    excl    = (int*)(ws + 67040000);     // [N]
    int*    parts   = (int*)(ws + 67200000);     // [<=256]
    float*  gate    = (float*)(ws + 67204096);   // [N]
    float*  pooled  = (float*)(ws + 67364096);   // [64,64]
    float4* ea_s    = (float4*)(ws + 67380480);  // [E,32] floats, CSR-ordered (optional)
    const bool sorted_ea = ws_size >= (size_t)67380480 + (size_t)E * 32 * 4;

    auto cdiv = [](int a, int b) { return (a + b - 1) / b; };
    const int NB = cdiv(N, 256);
    const dim3 gemmG(N / 64, 2);
    const int AGGB = cdiv(N, 4);

    // ---- CSR build (once; graph shared by all 3 layers) ----
    k_fill<<<NB, 256, 0, stream>>>((unsigned*)deg, N, 0u);
    k_hist<<<cdiv(E, 256), 256, 0, stream>>>(ei, E, deg);
    k_scan_blocks<<<NB, 256, 0, stream>>>(deg, N, excl, parts);
    k_scan_parts<<<1, 256, 0, stream>>>(parts, NB);
    k_scan_add<<<NB, 256, 0, stream>>>(excl, parts, row_ptr, cursor, N);
    k_scatter<<<cdiv(E, 256), 256, 0, stream>>>(ei, E, cursor, elist);
    if (sorted_ea)
        k_reorder<<<cdiv(E * 8, 256), 256, 0, stream>>>(elist, ea, E, ea_s);

    // ---- layer 1 ----
    k_gemm2<128, 8><<<gemmG, 256, 0, stream>>>(x, W1l, b1l, W1r, b1r, bufA, bufB);
    if (sorted_ea)
        k_agg<2, true, true><<<AGGB, 256, 0, stream>>>(bufA, bufB, ea, ea_s, elist, row_ptr, deg, W1e, att1, bias1, bufH, N);
    else
        k_agg<2, true, false><<<AGGB, 256, 0, stream>>>(bufA, bufB, ea, ea_s, elist, row_ptr, deg, W1e, att1, bias1, bufH, N);

    // ---- layer 2 ----
    k_gemm2<128, 8><<<gemmG, 256, 0, stream>>>(bufH, W2l, b2l, W2r, b2r, bufA, bufB);
    if (sorted_ea)
        k_agg<2, true, true><<<AGGB, 256, 0, stream>>>(bufA, bufB, ea, ea_s, elist, row_ptr, deg, W2e, att2, bias2, bufH, N);
    else
        k_agg<2, true, false><<<AGGB, 256, 0, stream>>>(bufA, bufB, ea, ea_s, elist, row_ptr, deg, W2e, att2, bias2, bufH, N);

    // ---- layer 3 ----
    k_gemm2<64, 4><<<gemmG, 256, 0, stream>>>(bufH, W3l, b3l, W3r, b3r, bufA, bufB);
    if (sorted_ea)
        k_agg<1, false, true><<<AGGB, 256, 0, stream>>>(bufA, bufB, ea, ea_s, elist, row_ptr, deg, W3e, att3, bias3, bufH, N);
    else
        k_agg<1, false, false><<<AGGB, 256, 0, stream>>>(bufA, bufB, ea, ea_s, elist, row_ptr, deg, W3e, att3, bias3, bufH, N);

    // ---- attentional pooling + regressor ----
    k_gate<<<N / 64, 256, 0, stream>>>(bufH, G1w, G1b, G2w, G2b, gate, N);
    k_pool<<<64, 256, 0, stream>>>(bufH, gate, batch, pooled, N);
    k_final<<<1, 64, 0, stream>>>(pooled, Wreg, breg, (float*)d_out);
}

// Round 2
// 1627.630 us; speedup vs baseline: 1.0412x; 1.0412x over previous
//
#include <hip/hip_runtime.h>

__global__ void k_fill(unsigned* p, int n, unsigned v) {
    int i = blockIdx.x * blockDim.x + threadIdx.x;
    if (i < n) p[i] = v;
}

// ---------------- CSR build (graph identical across layers; built once) ----------------
__global__ void k_hist(const int* __restrict__ ei, int E, int* __restrict__ deg) {
    int e = blockIdx.x * blockDim.x + threadIdx.x;
    if (e < E) atomicAdd(&deg[ei[E + e]], 1);
}

__global__ void k_scan_blocks(const int* __restrict__ deg, int N,
                              int* __restrict__ excl, int* __restrict__ parts) {
    __shared__ int s[256];
    int t = threadIdx.x, i = blockIdx.x * 256 + t;
    int v = (i < N) ? deg[i] : 0;
    s[t] = v;
    __syncthreads();
    int acc = v;
    for (int off = 1; off < 256; off <<= 1) {
        int add = (t >= off) ? s[t - off] : 0;
        __syncthreads();
        acc += add;
        s[t] = acc;
        __syncthreads();
    }
    if (i < N) excl[i] = acc - v;
    if (t == 255) parts[blockIdx.x] = acc;
}

__global__ void k_scan_parts(int* __restrict__ parts, int nb) {
    __shared__ int s[256];
    int t = threadIdx.x;
    int v = (t < nb) ? parts[t] : 0;
    s[t] = v;
    __syncthreads();
    int acc = v;
    for (int off = 1; off < 256; off <<= 1) {
        int add = (t >= off) ? s[t - off] : 0;
        __syncthreads();
        acc += add;
        s[t] = acc;
        __syncthreads();
    }
    if (t < nb) parts[t] = acc - v;
}

__global__ void k_scan_add(const int* __restrict__ excl, const int* __restrict__ parts,
                           int* __restrict__ row_ptr, int* __restrict__ cursor, int N) {
    int i = blockIdx.x * blockDim.x + threadIdx.x;
    if (i >= N) return;
    int r = excl[i] + parts[i >> 8];
    row_ptr[i] = r;
    cursor[i] = r;
}

__global__ void k_scatter(const int* __restrict__ ei, int E, int* __restrict__ cursor,
                          int2* __restrict__ elist) {
    int e = blockIdx.x * blockDim.x + threadIdx.x;
    if (e >= E) return;
    int d = ei[E + e];
    int j = atomicAdd(&cursor[d], 1);
    elist[j] = make_int2(ei[e], e);
}

// permute edge_attr into CSR order: ea_s[j] = ea[elist[j].y]  (8 threads per edge)
__global__ void k_reorder(const int2* __restrict__ elist, const float* __restrict__ ea, int E,
                          float4* __restrict__ ea_s) {
    int idx = blockIdx.x * blockDim.x + threadIdx.x;
    int j = idx >> 3, q = idx & 7;
    if (j >= E) return;
    ea_s[(size_t)j * 8 + q] = ((const float4*)ea)[(size_t)elist[j].y * 8 + q];
}

// ---------------- Dual GEMM: out{l,r} = A @ W{l,r} + b{l,r} ----------------
template <int M, int RW>
__global__ __launch_bounds__(256) void k_gemm2(const float* __restrict__ A,
                                               const float* __restrict__ Wl, const float* __restrict__ bl,
                                               const float* __restrict__ Wr, const float* __restrict__ br,
                                               float* __restrict__ outl, float* __restrict__ outr) {
    constexpr int TX = M / 4;
    __shared__ float sA[32][68];
    __shared__ float sW[32][M];
    const float* W    = blockIdx.y ? Wr : Wl;
    const float* bias = blockIdx.y ? br : bl;
    float* out        = blockIdx.y ? outr : outl;
    int t = threadIdx.x;
    int tx = t % TX, ty = t / TX;
    int r0 = blockIdx.x * 64;
    float acc[RW][4] = {};
    for (int kt = 0; kt < 128; kt += 32) {
        for (int l = t; l < 512; l += 256) {
            int row = l >> 3, kq = (l & 7) << 2;
            float4 a = *(const float4*)&A[(size_t)(r0 + row) * 128 + kt + kq];
            sA[kq + 0][row] = a.x; sA[kq + 1][row] = a.y;
            sA[kq + 2][row] = a.z; sA[kq + 3][row] = a.w;
        }
        for (int l = t; l < 32 * M / 4; l += 256) {
            int kk = (l * 4) / M, cc = (l * 4) % M;
            *(float4*)&sW[kk][cc] = *(const float4*)&W[(size_t)(kt + kk) * M + cc];
        }
        __syncthreads();
#pragma unroll
        for (int k = 0; k < 32; k++) {
            float4 w = *(float4*)&sW[k][tx * 4];
            float ar[RW];
#pragma unroll
            for (int i = 0; i < RW; i += 4) {
                float4 a = *(float4*)&sA[k][ty * RW + i];
                ar[i] = a.x; ar[i + 1] = a.y; ar[i + 2] = a.z; ar[i + 3] = a.w;
            }
#pragma unroll
            for (int i = 0; i < RW; i++) {
                acc[i][0] += ar[i] * w.x; acc[i][1] += ar[i] * w.y;
                acc[i][2] += ar[i] * w.z; acc[i][3] += ar[i] * w.w;
            }
        }
        __syncthreads();
    }
    float4 b = *(const float4*)&bias[tx * 4];
#pragma unroll
    for (int i = 0; i < RW; i++) {
        float4 v;
        v.x = acc[i][0] + b.x; v.y = acc[i][1] + b.y;
        v.z = acc[i][2] + b.z; v.w = acc[i][3] + b.w;
        *(float4*)&out[(size_t)(r0 + ty * RW + i) * M + tx * 4] = v;
    }
}

// ---------------- Fused per-dst GATv2 aggregation (CSR, zero atomics) ----------------
// v3: node work split across waves for latency hiding.
//   H==2: block = ONE node, 4 waves = (head h, edge-parity eh). Each wave owns one
//         head's 64 channels (rWe = 32 floats -> register-resident, no remat) and
//         processes every other edge. 4x wave count vs round-0, half-length edge loop.
//   H==1: block = TWO nodes, 2 waves per node (edge parity).
//   Edge-parity halves combine acc/den through a 520B LDS epilogue (denominator is an
//   order-independent sum; softmax unchanged).
//   ea loads batched into r[8] before the FMA block (two independent ee chains) so the
//   8 uniform loads issue together instead of load->wait->FMA serialization.
template <int H, bool RELU, bool SORTED>
__global__ __launch_bounds__(256) void k_agg(const float* __restrict__ xl, const float* __restrict__ xr,
                                             const float* __restrict__ ea, const float4* __restrict__ ea_s,
                                             const int2* __restrict__ elist,
                                             const int* __restrict__ row_ptr, const int* __restrict__ deg,
                                             const float* __restrict__ We, const float* __restrict__ att,
                                             const float* __restrict__ bias, float* __restrict__ out, int N) {
    constexpr int HC = H * 64;
    __shared__ float sAcc[2][64];
    __shared__ float sDen[2];
    int tid = threadIdx.x, wv = tid >> 6, lane = tid & 63;
    int h, eh, n, slotIdx;
    if constexpr (H == 2) {
        h = wv >> 1; eh = wv & 1; n = blockIdx.x; slotIdx = h;
    } else {
        h = 0; eh = wv & 1; n = blockIdx.x * 2 + (wv >> 1); slotIdx = wv >> 1;
    }
    int col = h * 64 + lane;

    float rWe[32];
#pragma unroll
    for (int k = 0; k < 32; k++) rWe[k] = We[k * HC + col];
    float attv = att[col], bv = bias[col];

    bool alive = n < N;
    float xrv = 0.f;
    int start = 0, d = 0;
    if (alive) {
        xrv = xr[(size_t)n * HC + col];
        start = row_ptr[n];
        d = deg[n];
    }

    float acc = 0.f, den = 0.f;
    for (int j = eh; j < d; j += 2) {
        int slot = start + j;
        int2 sp = elist[slot];
        const float4* eap = SORTED ? (ea_s + (size_t)slot * 8)
                                   : (const float4*)(ea + (size_t)sp.y * 32);
        float4 r[8];
#pragma unroll
        for (int q = 0; q < 8; q++) r[q] = eap[q];
        float xlv = xl[(size_t)sp.x * HC + col];
        float eeA = 0.f, eeB = 0.f;   // two independent chains -> half dep latency
#pragma unroll
        for (int q = 0; q < 8; q += 2) {
            eeA = fmaf(r[q].x, rWe[q * 4 + 0], eeA);
            eeA = fmaf(r[q].y, rWe[q * 4 + 1], eeA);
            eeA = fmaf(r[q].z, rWe[q * 4 + 2], eeA);
            eeA = fmaf(r[q].w, rWe[q * 4 + 3], eeA);
            eeB = fmaf(r[q + 1].x, rWe[q * 4 + 4], eeB);
            eeB = fmaf(r[q + 1].y, rWe[q * 4 + 5], eeB);
            eeB = fmaf(r[q + 1].z, rWe[q * 4 + 6], eeB);
            eeB = fmaf(r[q + 1].w, rWe[q * 4 + 7], eeB);
        }
        float v = xlv + xrv + (eeA + eeB);
        v = v > 0.f ? v : 0.2f * v;
        float p = attv * v;
#pragma unroll
        for (int m = 32; m; m >>= 1) p += __shfl_xor(p, m);
        float ex = __expf(p);
        acc = fmaf(ex, xlv, acc);
        den += ex;
    }

    if (eh == 1) {
        sAcc[slotIdx][lane] = acc;
        if (lane == 0) sDen[slotIdx] = den;   // den is wave-uniform after butterfly
    }
    __syncthreads();
    if (eh == 0 && alive) {
        float a = acc + sAcc[slotIdx][lane];
        float dd = den + sDen[slotIdx] + 1e-16f;
        float o = a / dd + bv;
        if (RELU) o = fmaxf(o, 0.f);
        out[(size_t)n * HC + col] = o;
    }
}

// ---------------- gate MLP: gate[n] = exp(relu(h[n]@G1w+G1b)@G2w + G2b) ----------------
__global__ __launch_bounds__(256) void k_gate(const float* __restrict__ h, const float* __restrict__ G1w,
                                              const float* __restrict__ G1b, const float* __restrict__ G2w,
                                              const float* __restrict__ G2b,
                                              float* __restrict__ gate, int N) {
    __shared__ float sH[64][64];
    __shared__ float part[64][2];
    int t = threadIdx.x;
    int n0 = blockIdx.x * 64;
    for (int l = t; l < 1024; l += 256) {
        float4 v = ((const float4*)(h + (size_t)n0 * 64))[l];
        int n = l >> 4, kq = (l & 15) << 2;
        *(float4*)&sH[n][kq] = v;
    }
    int c = t & 127, half = t >> 7;
    float rW[64];
#pragma unroll
    for (int k = 0; k < 64; k++) rW[k] = G1w[k * 128 + c];
    float g1b = G1b[c], g2w = G2w[c];
    __syncthreads();
    for (int nn = 0; nn < 32; nn++) {
        int n = half * 32 + nn;
        float acc = g1b;
#pragma unroll
        for (int k = 0; k < 64; k += 4) {
            float4 hv = *(const float4*)&sH[n][k];
            acc = fmaf(hv.x, rW[k], acc);
            acc = fmaf(hv.y, rW[k + 1], acc);
            acc = fmaf(hv.z, rW[k + 2], acc);
            acc = fmaf(hv.w, rW[k + 3], acc);
        }
        acc = acc > 0.f ? acc : 0.f;
        float p = acc * g2w;
#pragma unroll
        for (int m = 32; m; m >>= 1) p += __shfl_xor(p, m);
        if ((t & 63) == 0) part[n][(t >> 6) & 1] = p;
    }
    __syncthreads();
    if (t < 64) gate[n0 + t] = __expf(part[t][0] + part[t][1] + G2b[0]);
}

// ---------------- pooling: one block per graph (batch sorted -> binary search range) ----------------
__global__ __launch_bounds__(256) void k_pool(const float* __restrict__ h, const float* __restrict__ gate,
                                              const int* __restrict__ batch,
                                              float* __restrict__ pooled, int N) {
    int g = blockIdx.x;
    int lo = 0, hi = N;
    while (lo < hi) { int mid = (lo + hi) >> 1; if (batch[mid] < g) lo = mid + 1; else hi = mid; }
    int start = lo;
    lo = 0; hi = N;
    while (lo < hi) { int mid = (lo + hi) >> 1; if (batch[mid] < g + 1) lo = mid + 1; else hi = mid; }
    int end = lo;
    int t = threadIdx.x, wv = t >> 6, lane = t & 63;
    float acc = 0.f, den = 0.f;
    for (int n = start + wv; n < end; n += 4) {
        float gv = gate[n];
        acc = fmaf(gv, h[(size_t)n * 64 + lane], acc);
        den += gv;   // same across lanes of this wave
    }
    __shared__ float sacc[4][64];
    __shared__ float sden[4];
    sacc[wv][lane] = acc;
    if (lane == 0) sden[wv] = den;
    __syncthreads();
    if (wv == 0) {
        float a = sacc[0][lane] + sacc[1][lane] + sacc[2][lane] + sacc[3][lane];
        float d = sden[0] + sden[1] + sden[2] + sden[3] + 1e-16f;
        pooled[g * 64 + lane] = a / d;
    }
}

__global__ void k_final(const float* __restrict__ pooled, const float* __restrict__ Wreg,
                        const float* __restrict__ breg, float* __restrict__ out) {
    int g = threadIdx.x;
    float acc = breg[0];
    for (int c = 0; c < 64; c++) acc += pooled[g * 64 + c] * Wreg[c];
    out[g] = acc;
}

extern "C" void kernel_launch(void* const* d_in, const int* in_sizes, int n_in,
                              void* d_out, int out_size, void* d_ws, size_t ws_size,
                              hipStream_t stream) {
    const float* x  = (const float*)d_in[0];
    const float* ea = (const float*)d_in[1];
    const int* ei    = (const int*)d_in[2];
    const int* batch = (const int*)d_in[3];
    auto ff = [&](int i) { return (const float*)d_in[i]; };
    const float *W1l = ff(4), *b1l = ff(5), *W1r = ff(6), *b1r = ff(7), *W1e = ff(8),
                *att1 = ff(9), *bias1 = ff(10);
    const float *W2l = ff(11), *b2l = ff(12), *W2r = ff(13), *b2r = ff(14), *W2e = ff(15),
                *att2 = ff(16), *bias2 = ff(17);
    const float *W3l = ff(18), *b3l = ff(19), *W3r = ff(20), *b3r = ff(21), *W3e = ff(22),
                *att3 = ff(23), *bias3 = ff(24);
    const float *G1w = ff(25), *G1b = ff(26), *G2w = ff(27), *G2b = ff(28), *Wreg = ff(29),
                *breg = ff(30);

    const int N = in_sizes[0] / 128;  // 40000
    const int E = in_sizes[2] / 2;    // 640000

    char* ws = (char*)d_ws;
    float*  bufA    = (float*)(ws);              // [N,128]
    float*  bufB    = (float*)(ws + 20480000);   // [N,128]
    float*  bufH    = (float*)(ws + 40960000);   // [N,128]
    int2*   elist   = (int2*)(ws + 61440000);    // [E] (src, edge_id)
    int*    row_ptr = (int*)(ws + 66560000);     // [N]
    int*    deg     = (int*)(ws + 66720000);     // [N]
    int*    cursor  = (int*)(ws + 66880000);     // [N]
    int*    excl    = (int*)(ws + 67040000);     // [N]
    int*    parts   = (int*)(ws + 67200000);     // [<=256]
    float*  gate    = (float*)(ws + 67204096);   // [N]
    float*  pooled  = (float*)(ws + 67364096);   // [64,64]
    float4* ea_s    = (float4*)(ws + 67380480);  // [E,32] floats, CSR-ordered (optional)
    const bool sorted_ea = ws_size >= (size_t)67380480 + (size_t)E * 32 * 4;

    auto cdiv = [](int a, int b) { return (a + b - 1) / b; };
    const int NB = cdiv(N, 256);
    const dim3 gemmG(N / 64, 2);
    const int AGGB2 = N;            // H==2: one node per block (4 waves: 2 heads x 2 parities)
    const int AGGB1 = cdiv(N, 2);   // H==1: two nodes per block (2 waves each)

    // ---- CSR build (once; graph shared by all 3 layers) ----
    k_fill<<<NB, 256, 0, stream>>>((unsigned*)deg, N, 0u);
    k_hist<<<cdiv(E, 256), 256, 0, stream>>>(ei, E, deg);
    k_scan_blocks<<<NB, 256, 0, stream>>>(deg, N, excl, parts);
    k_scan_parts<<<1, 256, 0, stream>>>(parts, NB);
    k_scan_add<<<NB, 256, 0, stream>>>(excl, parts, row_ptr, cursor, N);
    k_scatter<<<cdiv(E, 256), 256, 0, stream>>>(ei, E, cursor, elist);
    if (sorted_ea)
        k_reorder<<<cdiv(E * 8, 256), 256, 0, stream>>>(elist, ea, E, ea_s);

    // ---- layer 1 ----
    k_gemm2<128, 8><<<gemmG, 256, 0, stream>>>(x, W1l, b1l, W1r, b1r, bufA, bufB);
    if (sorted_ea)
        k_agg<2, true, true><<<AGGB2, 256, 0, stream>>>(bufA, bufB, ea, ea_s, elist, row_ptr, deg, W1e, att1, bias1, bufH, N);
    else
        k_agg<2, true, false><<<AGGB2, 256, 0, stream>>>(bufA, bufB, ea, ea_s, elist, row_ptr, deg, W1e, att1, bias1, bufH, N);

    // ---- layer 2 ----
    k_gemm2<128, 8><<<gemmG, 256, 0, stream>>>(bufH, W2l, b2l, W2r, b2r, bufA, bufB);
    if (sorted_ea)
        k_agg<2, true, true><<<AGGB2, 256, 0, stream>>>(bufA, bufB, ea, ea_s, elist, row_ptr, deg, W2e, att2, bias2, bufH, N);
    else
        k_agg<2, true, false><<<AGGB2, 256, 0, stream>>>(bufA, bufB, ea, ea_s, elist, row_ptr, deg, W2e, att2, bias2, bufH, N);

    // ---- layer 3 ----
    k_gemm2<64, 4><<<gemmG, 256, 0, stream>>>(bufH, W3l, b3l, W3r, b3r, bufA, bufB);
    if (sorted_ea)
        k_agg<1, false, true><<<AGGB1, 256, 0, stream>>>(bufA, bufB, ea, ea_s, elist, row_ptr, deg, W3e, att3, bias3, bufH, N);
    else
        k_agg<1, false, false><<<AGGB1, 256, 0, stream>>>(bufA, bufB, ea, ea_s, elist, row_ptr, deg, W3e, att3, bias3, bufH, N);

    // ---- attentional pooling + regressor ----
    k_gate<<<N / 64, 256, 0, stream>>>(bufH, G1w, G1b, G2w, G2b, gate, N);
    k_pool<<<64, 256, 0, stream>>>(bufH, gate, batch, pooled, N);
    k_final<<<1, 64, 0, stream>>>(pooled, Wreg, breg, (float*)d_out);
}

// Round 3
// 1369.810 us; speedup vs baseline: 1.2372x; 1.1882x over previous
//
#include <hip/hip_runtime.h>

__global__ void k_fill(unsigned* p, int n, unsigned v) {
    int i = blockIdx.x * blockDim.x + threadIdx.x;
    if (i < n) p[i] = v;
}

// ---------------- CSR build (graph identical across layers; built once) ----------------
__global__ void k_hist(const int* __restrict__ ei, int E, int* __restrict__ deg) {
    int e = blockIdx.x * blockDim.x + threadIdx.x;
    if (e < E) atomicAdd(&deg[ei[E + e]], 1);
}

__global__ void k_scan_blocks(const int* __restrict__ deg, int N,
                              int* __restrict__ excl, int* __restrict__ parts) {
    __shared__ int s[256];
    int t = threadIdx.x, i = blockIdx.x * 256 + t;
    int v = (i < N) ? deg[i] : 0;
    s[t] = v;
    __syncthreads();
    int acc = v;
    for (int off = 1; off < 256; off <<= 1) {
        int add = (t >= off) ? s[t - off] : 0;
        __syncthreads();
        acc += add;
        s[t] = acc;
        __syncthreads();
    }
    if (i < N) excl[i] = acc - v;
    if (t == 255) parts[blockIdx.x] = acc;
}

__global__ void k_scan_parts(int* __restrict__ parts, int nb) {
    __shared__ int s[256];
    int t = threadIdx.x;
    int v = (t < nb) ? parts[t] : 0;
    s[t] = v;
    __syncthreads();
    int acc = v;
    for (int off = 1; off < 256; off <<= 1) {
        int add = (t >= off) ? s[t - off] : 0;
        __syncthreads();
        acc += add;
        s[t] = acc;
        __syncthreads();
    }
    if (t < nb) parts[t] = acc - v;
}

__global__ void k_scan_add(const int* __restrict__ excl, const int* __restrict__ parts,
                           int* __restrict__ row_ptr, int* __restrict__ cursor, int N) {
    int i = blockIdx.x * blockDim.x + threadIdx.x;
    if (i >= N) return;
    int r = excl[i] + parts[i >> 8];
    row_ptr[i] = r;
    cursor[i] = r;
}

__global__ void k_scatter(const int* __restrict__ ei, int E, int* __restrict__ cursor,
                          int2* __restrict__ elist) {
    int e = blockIdx.x * blockDim.x + threadIdx.x;
    if (e >= E) return;
    int d = ei[E + e];
    int j = atomicAdd(&cursor[d], 1);
    elist[j] = make_int2(ei[e], e);
}

// ---------------- Dual GEMM: out{l,r} = A @ W{l,r} + b{l,r} ----------------
template <int M, int RW>
__global__ __launch_bounds__(256) void k_gemm2(const float* __restrict__ A,
                                               const float* __restrict__ Wl, const float* __restrict__ bl,
                                               const float* __restrict__ Wr, const float* __restrict__ br,
                                               float* __restrict__ outl, float* __restrict__ outr) {
    constexpr int TX = M / 4;
    __shared__ float sA[32][68];
    __shared__ float sW[32][M];
    const float* W    = blockIdx.y ? Wr : Wl;
    const float* bias = blockIdx.y ? br : bl;
    float* out        = blockIdx.y ? outr : outl;
    int t = threadIdx.x;
    int tx = t % TX, ty = t / TX;
    int r0 = blockIdx.x * 64;
    float acc[RW][4] = {};
    for (int kt = 0; kt < 128; kt += 32) {
        for (int l = t; l < 512; l += 256) {
            int row = l >> 3, kq = (l & 7) << 2;
            float4 a = *(const float4*)&A[(size_t)(r0 + row) * 128 + kt + kq];
            sA[kq + 0][row] = a.x; sA[kq + 1][row] = a.y;
            sA[kq + 2][row] = a.z; sA[kq + 3][row] = a.w;
        }
        for (int l = t; l < 32 * M / 4; l += 256) {
            int kk = (l * 4) / M, cc = (l * 4) % M;
            *(float4*)&sW[kk][cc] = *(const float4*)&W[(size_t)(kt + kk) * M + cc];
        }
        __syncthreads();
#pragma unroll
        for (int k = 0; k < 32; k++) {
            float4 w = *(float4*)&sW[k][tx * 4];
            float ar[RW];
#pragma unroll
            for (int i = 0; i < RW; i += 4) {
                float4 a = *(float4*)&sA[k][ty * RW + i];
                ar[i] = a.x; ar[i + 1] = a.y; ar[i + 2] = a.z; ar[i + 3] = a.w;
            }
#pragma unroll
            for (int i = 0; i < RW; i++) {
                acc[i][0] += ar[i] * w.x; acc[i][1] += ar[i] * w.y;
                acc[i][2] += ar[i] * w.z; acc[i][3] += ar[i] * w.w;
            }
        }
        __syncthreads();
    }
    float4 b = *(const float4*)&bias[tx * 4];
#pragma unroll
    for (int i = 0; i < RW; i++) {
        float4 v;
        v.x = acc[i][0] + b.x; v.y = acc[i][1] + b.y;
        v.z = acc[i][2] + b.z; v.w = acc[i][3] + b.w;
        *(float4*)&out[(size_t)(r0 + ty * RW + i) * M + tx * 4] = v;
    }
}

// ---------------- Edge transform GEMM: ee[slot] = ea[elist[slot].y] @ We ----------------
// Streams CSR slots [s0, s1) of chunk [n0, n1); writes ee chunk-relative (slot - s0).
// Converts the agg loop's 8 broadcast ea loads + 32 FMAs per edge-visit into one
// coalesced per-lane float2 read.
template <int HC>
__global__ __launch_bounds__(256) void k_edge_gemm(const float* __restrict__ ea,
                                                   const int2* __restrict__ elist,
                                                   const int* __restrict__ row_ptr,
                                                   const float* __restrict__ We,
                                                   float* __restrict__ ee,
                                                   int n0, int n1, int Ntot, int E) {
    int s0 = row_ptr[n0];
    int s1 = (n1 >= Ntot) ? E : row_ptr[n1];
    int sb = s0 + blockIdx.x * 64;
    if (sb >= s1) return;
    __shared__ float sA[64][33];
    __shared__ float sW[32][HC];
    int t = threadIdx.x;
    for (int l = t; l < 512; l += 256) {      // 64 rows x 8 float4
        int row = l >> 3, q = l & 7;
        int s = sb + row;
        int eid = (s < s1) ? elist[s].y : 0;
        float4 a = *(const float4*)&ea[(size_t)eid * 32 + q * 4];
        sA[row][q * 4 + 0] = a.x; sA[row][q * 4 + 1] = a.y;
        sA[row][q * 4 + 2] = a.z; sA[row][q * 4 + 3] = a.w;
    }
    for (int l = t; l < 32 * HC / 4; l += 256) {
        int k = (l * 4) / HC, c = (l * 4) % HC;
        *(float4*)&sW[k][c] = *(const float4*)&We[k * HC + c];
    }
    __syncthreads();
    constexpr int CG = HC / 4;      // col groups of 4
    constexpr int RPT = CG / 4;     // rows per thread (HC=128 -> 8, HC=64 -> 4)
    int tx = t % CG, ty = t / CG;
    float acc[RPT][4] = {};
#pragma unroll
    for (int k = 0; k < 32; k++) {
        float4 w = *(float4*)&sW[k][tx * 4];
#pragma unroll
        for (int i = 0; i < RPT; i++) {
            float a = sA[ty * RPT + i][k];
            acc[i][0] = fmaf(a, w.x, acc[i][0]);
            acc[i][1] = fmaf(a, w.y, acc[i][1]);
            acc[i][2] = fmaf(a, w.z, acc[i][2]);
            acc[i][3] = fmaf(a, w.w, acc[i][3]);
        }
    }
#pragma unroll
    for (int i = 0; i < RPT; i++) {
        int s = sb + ty * RPT + i;
        if (s < s1)
            *(float4*)&ee[(size_t)(s - s0) * HC + tx * 4] =
                make_float4(acc[i][0], acc[i][1], acc[i][2], acc[i][3]);
    }
}

// ---------------- Lean fused GATv2 aggregation (uses precomputed ee) ----------------
// 2 channels per lane. H==2: lane-half = head (both heads of an edge in one visit).
// H==1: lane-half = edge parity within the wave (2 edges per visit).
// Block = 4 waves = 2 nodes x 2 parity waves; parity halves merge via LDS.
// 2-deep pipeline: elist prefetched 2 edges ahead (linear addr), ee/xl 1 ahead,
// so the elist->xl dependent gather is off the per-iteration critical path.
template <int H, bool RELU>
__global__ __launch_bounds__(256) void k_aggv(const float* __restrict__ xl, const float* __restrict__ xr,
                                              const float* __restrict__ ee,
                                              const int2* __restrict__ elist,
                                              const int* __restrict__ row_ptr, const int* __restrict__ deg,
                                              const float* __restrict__ att, const float* __restrict__ bias,
                                              float* __restrict__ out, int n0, int n1) {
    constexpr int HC = H * 64;
    __shared__ float2 sAcc[2][64];
    __shared__ float  sDen[2][64];
    int tid = threadIdx.x, wv = tid >> 6, lane = tid & 63;
    int ns = wv >> 1, eh = wv & 1;
    int n = n0 + blockIdx.x * 2 + ns;
    bool alive = n < n1;
    int hf = lane >> 5, c2 = lane & 31;
    int col = (H == 2) ? (hf * 64 + 2 * c2) : (2 * c2);
    float2 attv = *(const float2*)&att[col];
    int s0 = row_ptr[n0];
    float2 xrv = make_float2(0.f, 0.f);
    int start = 0, d = 0;
    if (alive) {
        xrv = *(const float2*)&xr[(size_t)n * HC + col];
        start = row_ptr[n];
        d = deg[n];
    }
    float2 acc = make_float2(0.f, 0.f);
    float den = 0.f;

    const int jstep = (H == 2) ? 2 : 4;
    int jc = (H == 2) ? eh : (2 * eh + hf);
    bool okc = jc < d;
    int sC = start + jc;
    int sN = sC + jstep;
    int spx = okc ? elist[sC].x : 0;
    float2 eeC = okc ? *(const float2*)&ee[(size_t)(sC - s0) * HC + col] : make_float2(0.f, 0.f);
    float2 xlC = okc ? *(const float2*)&xl[(size_t)spx * HC + col] : make_float2(0.f, 0.f);
    bool okn = (jc + jstep) < d;
    int spxN = okn ? elist[sN].x : 0;

    while (okc) {
        bool okn2 = (jc + 2 * jstep) < d;
        int sN2 = sN + jstep;
        int spxN2 = okn2 ? elist[sN2].x : 0;
        float2 eeN = okn ? *(const float2*)&ee[(size_t)(sN - s0) * HC + col] : make_float2(0.f, 0.f);
        float2 xlN = okn ? *(const float2*)&xl[(size_t)spxN * HC + col] : make_float2(0.f, 0.f);

        float v0 = xlC.x + xrv.x + eeC.x;
        float v1 = xlC.y + xrv.y + eeC.y;
        v0 = v0 > 0.f ? v0 : 0.2f * v0;
        v1 = v1 > 0.f ? v1 : 0.2f * v1;
        float p = fmaf(attv.x, v0, attv.y * v1);
#pragma unroll
        for (int m = 16; m; m >>= 1) p += __shfl_xor(p, m);
        float ex = __expf(p);
        acc.x = fmaf(ex, xlC.x, acc.x);
        acc.y = fmaf(ex, xlC.y, acc.y);
        den += ex;

        jc += jstep; sC = sN; sN = sN2;
        xlC = xlN; eeC = eeN; spxN = spxN2;
        okc = okn; okn = okn2;
    }

    if constexpr (H == 1) {   // halves hold disjoint edge subsets of same channels
        acc.x += __shfl_xor(acc.x, 32);
        acc.y += __shfl_xor(acc.y, 32);
        den   += __shfl_xor(den, 32);
    }
    if (eh == 1) { sAcc[ns][lane] = acc; sDen[ns][lane] = den; }
    __syncthreads();
    if (eh == 0 && alive) {
        float2 a = sAcc[ns][lane];
        float dd = sDen[ns][lane];
        float dsum = den + dd + 1e-16f;
        float2 bv = *(const float2*)&bias[col];
        float o0 = (acc.x + a.x) / dsum + bv.x;
        float o1 = (acc.y + a.y) / dsum + bv.y;
        if (RELU) { o0 = fmaxf(o0, 0.f); o1 = fmaxf(o1, 0.f); }
        if (H == 2 || hf == 0)
            *(float2*)&out[(size_t)n * HC + col] = make_float2(o0, o1);
    }
}

// ---------------- Fallback agg (round-0 structure, unsorted ea) — tiny-workspace path ----
template <int H, bool RELU>
__global__ __launch_bounds__(256) void k_agg_fb(const float* __restrict__ xl, const float* __restrict__ xr,
                                                const float* __restrict__ ea,
                                                const int2* __restrict__ elist,
                                                const int* __restrict__ row_ptr, const int* __restrict__ deg,
                                                const float* __restrict__ We, const float* __restrict__ att,
                                                const float* __restrict__ bias, float* __restrict__ out, int N) {
    constexpr int HC = H * 64;
    int tid = threadIdx.x, wv = tid >> 6, lane = tid & 63;
    float rWe0[32], rWe1[H == 2 ? 32 : 1];
#pragma unroll
    for (int k = 0; k < 32; k++) rWe0[k] = We[k * HC + lane];
    if constexpr (H == 2) {
#pragma unroll
        for (int k = 0; k < 32; k++) rWe1[k] = We[k * HC + 64 + lane];
    }
    float att0 = att[lane], b0 = bias[lane];
    float att1 = 0.f, b1 = 0.f;
    if constexpr (H == 2) { att1 = att[64 + lane]; b1 = bias[64 + lane]; }
    int n = blockIdx.x * 4 + wv;
    if (n >= N) return;
    int start = row_ptr[n], d = deg[n];
    float xr0 = xr[(size_t)n * HC + lane];
    float xr1 = (H == 2) ? xr[(size_t)n * HC + 64 + lane] : 0.f;
    float acc0 = 0.f, acc1 = 0.f, den0 = 0.f, den1 = 0.f;
    for (int j = 0; j < d; j++) {
        int2 sp = elist[start + j];
        const float4* eap = (const float4*)(ea + (size_t)sp.y * 32);
        const float* xls = xl + (size_t)sp.x * HC;
        float xl0 = xls[lane];
        float xl1 = (H == 2) ? xls[64 + lane] : 0.f;
        float ee0 = 0.f, ee1 = 0.f;
#pragma unroll
        for (int kq = 0; kq < 8; kq++) {
            float4 v = eap[kq];
            ee0 = fmaf(v.x, rWe0[kq * 4 + 0], ee0);
            ee0 = fmaf(v.y, rWe0[kq * 4 + 1], ee0);
            ee0 = fmaf(v.z, rWe0[kq * 4 + 2], ee0);
            ee0 = fmaf(v.w, rWe0[kq * 4 + 3], ee0);
            if constexpr (H == 2) {
                ee1 = fmaf(v.x, rWe1[kq * 4 + 0], ee1);
                ee1 = fmaf(v.y, rWe1[kq * 4 + 1], ee1);
                ee1 = fmaf(v.z, rWe1[kq * 4 + 2], ee1);
                ee1 = fmaf(v.w, rWe1[kq * 4 + 3], ee1);
            }
        }
        float v0 = xl0 + xr0 + ee0;
        v0 = v0 > 0.f ? v0 : 0.2f * v0;
        float p0 = att0 * v0, p1 = 0.f;
        if constexpr (H == 2) {
            float v1 = xl1 + xr1 + ee1;
            v1 = v1 > 0.f ? v1 : 0.2f * v1;
            p1 = att1 * v1;
        }
#pragma unroll
        for (int m = 32; m; m >>= 1) {
            p0 += __shfl_xor(p0, m);
            if constexpr (H == 2) p1 += __shfl_xor(p1, m);
        }
        float ex0 = __expf(p0);
        acc0 = fmaf(ex0, xl0, acc0);
        den0 += ex0;
        if constexpr (H == 2) {
            float ex1 = __expf(p1);
            acc1 = fmaf(ex1, xl1, acc1);
            den1 += ex1;
        }
    }
    float o0 = acc0 / (den0 + 1e-16f) + b0;
    if (RELU) o0 = o0 > 0.f ? o0 : 0.f;
    out[(size_t)n * HC + lane] = o0;
    if constexpr (H == 2) {
        float o1 = acc1 / (den1 + 1e-16f) + b1;
        if (RELU) o1 = o1 > 0.f ? o1 : 0.f;
        out[(size_t)n * HC + 64 + lane] = o1;
    }
}

// ---------------- gate MLP ----------------
__global__ __launch_bounds__(256) void k_gate(const float* __restrict__ h, const float* __restrict__ G1w,
                                              const float* __restrict__ G1b, const float* __restrict__ G2w,
                                              const float* __restrict__ G2b,
                                              float* __restrict__ gate, int N) {
    __shared__ float sH[64][64];
    __shared__ float part[64][2];
    int t = threadIdx.x;
    int n0 = blockIdx.x * 64;
    for (int l = t; l < 1024; l += 256) {
        float4 v = ((const float4*)(h + (size_t)n0 * 64))[l];
        int n = l >> 4, kq = (l & 15) << 2;
        *(float4*)&sH[n][kq] = v;
    }
    int c = t & 127, half = t >> 7;
    float rW[64];
#pragma unroll
    for (int k = 0; k < 64; k++) rW[k] = G1w[k * 128 + c];
    float g1b = G1b[c], g2w = G2w[c];
    __syncthreads();
    for (int nn = 0; nn < 32; nn++) {
        int n = half * 32 + nn;
        float acc = g1b;
#pragma unroll
        for (int k = 0; k < 64; k += 4) {
            float4 hv = *(const float4*)&sH[n][k];
            acc = fmaf(hv.x, rW[k], acc);
            acc = fmaf(hv.y, rW[k + 1], acc);
            acc = fmaf(hv.z, rW[k + 2], acc);
            acc = fmaf(hv.w, rW[k + 3], acc);
        }
        acc = acc > 0.f ? acc : 0.f;
        float p = acc * g2w;
#pragma unroll
        for (int m = 32; m; m >>= 1) p += __shfl_xor(p, m);
        if ((t & 63) == 0) part[n][(t >> 6) & 1] = p;
    }
    __syncthreads();
    if (t < 64) gate[n0 + t] = __expf(part[t][0] + part[t][1] + G2b[0]);
}

// ---------------- pooling ----------------
__global__ __launch_bounds__(256) void k_pool(const float* __restrict__ h, const float* __restrict__ gate,
                                              const int* __restrict__ batch,
                                              float* __restrict__ pooled, int N) {
    int g = blockIdx.x;
    int lo = 0, hi = N;
    while (lo < hi) { int mid = (lo + hi) >> 1; if (batch[mid] < g) lo = mid + 1; else hi = mid; }
    int start = lo;
    lo = 0; hi = N;
    while (lo < hi) { int mid = (lo + hi) >> 1; if (batch[mid] < g + 1) lo = mid + 1; else hi = mid; }
    int end = lo;
    int t = threadIdx.x, wv = t >> 6, lane = t & 63;
    float acc = 0.f, den = 0.f;
    for (int n = start + wv; n < end; n += 4) {
        float gv = gate[n];
        acc = fmaf(gv, h[(size_t)n * 64 + lane], acc);
        den += gv;
    }
    __shared__ float sacc[4][64];
    __shared__ float sden[4];
    sacc[wv][lane] = acc;
    if (lane == 0) sden[wv] = den;
    __syncthreads();
    if (wv == 0) {
        float a = sacc[0][lane] + sacc[1][lane] + sacc[2][lane] + sacc[3][lane];
        float d = sden[0] + sden[1] + sden[2] + sden[3] + 1e-16f;
        pooled[g * 64 + lane] = a / d;
    }
}

__global__ void k_final(const float* __restrict__ pooled, const float* __restrict__ Wreg,
                        const float* __restrict__ breg, float* __restrict__ out) {
    int g = threadIdx.x;
    float acc = breg[0];
    for (int c = 0; c < 64; c++) acc += pooled[g * 64 + c] * Wreg[c];
    out[g] = acc;
}

// ---------------- host-side per-layer chunked launch ----------------
template <int H, bool RELU>
static void launch_layer_agg(const float* ea, const int2* elist, const int* row_ptr, const int* deg,
                             const float* We, const float* att, const float* bias,
                             const float* xl, const float* xr, float* outb, float* eebuf,
                             size_t avail, int N, int E, hipStream_t stream) {
    constexpr int HC = H * 64;
    size_t need = (size_t)E * HC * 4;
    int K = (avail >= need) ? 1 : (int)((need * 21 / 20 + avail - 1) / avail);
    size_t cap_slots = (K == 1) ? (size_t)E : avail / ((size_t)HC * 4);
    size_t cover = cap_slots < (size_t)E ? cap_slots : (size_t)E;
    int gb = (int)((cover + 63) / 64);
    for (int c = 0; c < K; c++) {
        int n0 = (int)((long long)N * c / K);
        int n1 = (int)((long long)N * (c + 1) / K);
        k_edge_gemm<HC><<<gb, 256, 0, stream>>>(ea, elist, row_ptr, We, eebuf, n0, n1, N, E);
        int nb = (n1 - n0 + 1) / 2;
        k_aggv<H, RELU><<<nb, 256, 0, stream>>>(xl, xr, eebuf, elist, row_ptr, deg, att, bias, outb, n0, n1);
    }
}

extern "C" void kernel_launch(void* const* d_in, const int* in_sizes, int n_in,
                              void* d_out, int out_size, void* d_ws, size_t ws_size,
                              hipStream_t stream) {
    const float* x  = (const float*)d_in[0];
    const float* ea = (const float*)d_in[1];
    const int* ei    = (const int*)d_in[2];
    const int* batch = (const int*)d_in[3];
    auto ff = [&](int i) { return (const float*)d_in[i]; };
    const float *W1l = ff(4), *b1l = ff(5), *W1r = ff(6), *b1r = ff(7), *W1e = ff(8),
                *att1 = ff(9), *bias1 = ff(10);
    const float *W2l = ff(11), *b2l = ff(12), *W2r = ff(13), *b2r = ff(14), *W2e = ff(15),
                *att2 = ff(16), *bias2 = ff(17);
    const float *W3l = ff(18), *b3l = ff(19), *W3r = ff(20), *b3r = ff(21), *W3e = ff(22),
                *att3 = ff(23), *bias3 = ff(24);
    const float *G1w = ff(25), *G1b = ff(26), *G2w = ff(27), *G2b = ff(28), *Wreg = ff(29),
                *breg = ff(30);

    const int N = in_sizes[0] / 128;  // 40000
    const int E = in_sizes[2] / 2;    // 640000

    char* ws = (char*)d_ws;
    float*  bufA    = (float*)(ws);              // [N,128]
    float*  bufB    = (float*)(ws + 20480000);   // [N,128]
    float*  bufH    = (float*)(ws + 40960000);   // [N,128]
    int2*   elist   = (int2*)(ws + 61440000);    // [E] (src, edge_id)
    int*    row_ptr = (int*)(ws + 66560000);     // [N]
    int*    deg     = (int*)(ws + 66720000);     // [N]
    int*    cursor  = (int*)(ws + 66880000);     // [N]
    int*    excl    = (int*)(ws + 67040000);     // [N]
    int*    parts   = (int*)(ws + 67200000);     // [<=256]
    float*  gate    = (float*)(ws + 67204096);   // [N]
    float*  pooled  = (float*)(ws + 67364096);   // [64,64]
    float*  eebuf   = (float*)(ws + 67380480);   // chunked ee[slots,HC], tail of workspace
    size_t avail = ws_size > (size_t)67380480 ? ws_size - (size_t)67380480 : 0;
    const bool newpath = avail >= ((size_t)64 << 20);   // >=64MB tail -> chunked ee path

    auto cdiv = [](int a, int b) { return (a + b - 1) / b; };
    const int NB = cdiv(N, 256);
    const dim3 gemmG(N / 64, 2);

    // ---- CSR build (once; graph shared by all 3 layers) ----
    k_fill<<<NB, 256, 0, stream>>>((unsigned*)deg, N, 0u);
    k_hist<<<cdiv(E, 256), 256, 0, stream>>>(ei, E, deg);
    k_scan_blocks<<<NB, 256, 0, stream>>>(deg, N, excl, parts);
    k_scan_parts<<<1, 256, 0, stream>>>(parts, NB);
    k_scan_add<<<NB, 256, 0, stream>>>(excl, parts, row_ptr, cursor, N);
    k_scatter<<<cdiv(E, 256), 256, 0, stream>>>(ei, E, cursor, elist);

    if (newpath) {
        // ---- layer 1 ----
        k_gemm2<128, 8><<<gemmG, 256, 0, stream>>>(x, W1l, b1l, W1r, b1r, bufA, bufB);
        launch_layer_agg<2, true>(ea, elist, row_ptr, deg, W1e, att1, bias1, bufA, bufB, bufH, eebuf, avail, N, E, stream);
        // ---- layer 2 ----
        k_gemm2<128, 8><<<gemmG, 256, 0, stream>>>(bufH, W2l, b2l, W2r, b2r, bufA, bufB);
        launch_layer_agg<2, true>(ea, elist, row_ptr, deg, W2e, att2, bias2, bufA, bufB, bufH, eebuf, avail, N, E, stream);
        // ---- layer 3 ----
        k_gemm2<64, 4><<<gemmG, 256, 0, stream>>>(bufH, W3l, b3l, W3r, b3r, bufA, bufB);
        launch_layer_agg<1, false>(ea, elist, row_ptr, deg, W3e, att3, bias3, bufA, bufB, bufH, eebuf, avail, N, E, stream);
    } else {
        const int AGGB = cdiv(N, 4);
        k_gemm2<128, 8><<<gemmG, 256, 0, stream>>>(x, W1l, b1l, W1r, b1r, bufA, bufB);
        k_agg_fb<2, true><<<AGGB, 256, 0, stream>>>(bufA, bufB, ea, elist, row_ptr, deg, W1e, att1, bias1, bufH, N);
        k_gemm2<128, 8><<<gemmG, 256, 0, stream>>>(bufH, W2l, b2l, W2r, b2r, bufA, bufB);
        k_agg_fb<2, true><<<AGGB, 256, 0, stream>>>(bufA, bufB, ea, elist, row_ptr, deg, W2e, att2, bias2, bufH, N);
        k_gemm2<64, 4><<<gemmG, 256, 0, stream>>>(bufH, W3l, b3l, W3r, b3r, bufA, bufB);
        k_agg_fb<1, false><<<AGGB, 256, 0, stream>>>(bufA, bufB, ea, elist, row_ptr, deg, W3e, att3, bias3, bufH, N);
    }

    // ---- attentional pooling + regressor ----
    k_gate<<<N / 64, 256, 0, stream>>>(bufH, G1w, G1b, G2w, G2b, gate, N);
    k_pool<<<64, 256, 0, stream>>>(bufH, gate, batch, pooled, N);
    k_final<<<1, 64, 0, stream>>>(pooled, Wreg, breg, (float*)d_out);
}